// Round 7
// baseline (27.795 us; speedup 1.0000x reference)
//
#include <hip/hip_runtime.h>
#include <math.h>

#define NY 74
#define NX 74
#define HH 512
#define WW 512
#define CC 3
#define BB 16

struct F3 { float a, b, c; };
typedef float v2f __attribute__((ext_vector_type(2)));

__device__ __forceinline__ void nt_store2(float* p, float a, float b) {
    v2f v; v.x = a; v.y = b;
    __builtin_nontemporal_store(v, (v2f*)p);
}

__global__ __launch_bounds__(256) void stb_kernel(
    const float* __restrict__ fmap, const float* __restrict__ theta,
    float* __restrict__ out, float* __restrict__ delta_out)
{
    // XCD-aware bijective swizzle (nwg = 8192, %8 == 0): each XCD gets a
    // contiguous band of rows -> fmap row-reuse stays in its private L2.
    const int nwg = BB * HH;
    const int bid = blockIdx.x;
    const int row = (bid & 7) * (nwg >> 3) + (bid >> 3);   // b*H + h
    const int h = row & (HH - 1);
    const int b = row >> 9;

    // 71/512 is exactly representable; replaces the reference's divide.
    const float inv_s = 71.0f / 512.0f;
    const float c6 = 1.0f / 6.0f;

    __shared__ float2 S[NX];

    const int t = threadIdx.x;
    // Prologue: 148 lanes, one (j, component) pair each.
    if (t < 2 * NX) {
        const int comp = (t >= NX) ? 1 : 0;
        const int j = t - comp * NX;
        float qy = (float)h * inv_s;
        float v = qy - floorf(qy);
        int py = (int)floorf(qy);
        float Bv0 = (((-v + 3.f) * v - 3.f) * v + 1.f) * c6;
        float Bv1 = ((3.f * v - 6.f) * v * v + 4.f) * c6;
        float Bv2 = (((-3.f * v + 3.f) * v + 3.f) * v + 1.f) * c6;
        float Bv3 = (v * v * v) * c6;

        const float* th = theta + (b * 2 + comp) * NY * NX;
        int base = py * NX + j;
        float s = Bv0 * th[base] + Bv1 * th[base + NX] +
                  Bv2 * th[base + 2 * NX] + Bv3 * th[base + 3 * NX];
        ((float*)S)[2 * j + comp] = s;   // even/odd split: conflict-free
    }
    __syncthreads();

    const float yh = (float)h;
    const float* fb = fmap + b * (HH * WW * CC);

    float o[6], dxy[2][2];

    #pragma unroll
    for (int k = 0; k < 2; ++k) {
        const int w = 2 * t + k;
        const float xw = (float)w;

        float qx = xw * inv_s;
        float u = qx - floorf(qx);
        int px = (int)floorf(qx);
        float Bu0 = (((-u + 3.f) * u - 3.f) * u + 1.f) * c6;
        float Bu1 = ((3.f * u - 6.f) * u * u + 4.f) * c6;
        float Bu2 = (((-3.f * u + 3.f) * u + 3.f) * u + 1.f) * c6;
        float Bu3 = (u * u * u) * c6;

        float2 s0 = S[px], s1 = S[px + 1], s2 = S[px + 2], s3 = S[px + 3];
        float dx = Bu0 * s0.x + Bu1 * s1.x + Bu2 * s2.x + Bu3 * s3.x;
        float dy = Bu0 * s0.y + Bu1 * s1.y + Bu2 * s2.y + Bu3 * s3.y;

        float xs = xw + dx;
        float ys = yh + dy;
        int x0 = (int)floorf(xs);
        int y0 = (int)floorf(ys);
        // reference clamp order: x1 from pre-clamp x0
        int x1 = min(max(x0 + 1, 0), WW - 1);
        int y1 = min(max(y0 + 1, 0), HH - 1);
        x0 = min(max(x0, 0), WW - 1);
        y0 = min(max(y0, 0), HH - 1);

        float wa = ((float)x1 - xs) * ((float)y1 - ys);
        float wb = ((float)x1 - xs) * (ys - (float)y0);
        float wc = (xs - (float)x0) * ((float)y1 - ys);
        float wd = (xs - (float)x0) * (ys - (float)y0);

        F3 Ia = *(const F3*)(fb + ((y0 << 9) + x0) * 3);
        F3 Ib = *(const F3*)(fb + ((y1 << 9) + x0) * 3);
        F3 Ic = *(const F3*)(fb + ((y0 << 9) + x1) * 3);
        F3 Id = *(const F3*)(fb + ((y1 << 9) + x1) * 3);

        o[k * 3 + 0] = wa * Ia.a + wb * Ib.a + wc * Ic.a + wd * Id.a;
        o[k * 3 + 1] = wa * Ia.b + wb * Ib.b + wc * Ic.b + wd * Id.b;
        o[k * 3 + 2] = wa * Ia.c + wb * Ib.c + wc * Ic.c + wd * Id.c;
        dxy[k][0] = dx;
        dxy[k][1] = dy;
    }

    // stores: 6 out floats (24B, 8B-aligned) + 2x float2 delta
    const int pix = (row << 9) + 2 * t;
    float* op = out + pix * 3;
    nt_store2(op + 0, o[0], o[1]);
    nt_store2(op + 2, o[2], o[3]);
    nt_store2(op + 4, o[4], o[5]);

    const int total = BB * HH * WW;
    nt_store2(delta_out + pix, dxy[0][0], dxy[1][0]);
    nt_store2(delta_out + total + pix, dxy[0][1], dxy[1][1]);
}

extern "C" void kernel_launch(void* const* d_in, const int* in_sizes, int n_in,
                              void* d_out, int out_size, void* d_ws, size_t ws_size,
                              hipStream_t stream) {
    const float* fmap  = (const float*)d_in[0];
    const float* theta = (const float*)d_in[1];
    float* out = (float*)d_out;
    float* delta = out + (size_t)BB * HH * WW * CC;

    dim3 grid(BB * HH), block(256);
    stb_kernel<<<grid, block, 0, stream>>>(fmap, theta, out, delta);
}

// Round 8
// 25.389 us; speedup vs baseline: 1.0948x; 1.0948x over previous
//
#include <hip/hip_runtime.h>
#include <math.h>

#define NY 74
#define NX 74
#define HH 512
#define WW 512
#define CC 3
#define BB 16

struct F3 { float a, b, c; };

__global__ __launch_bounds__(256) void stb_kernel(
    const float* __restrict__ fmap, const float* __restrict__ theta,
    float* __restrict__ out, float* __restrict__ delta_out)
{
    // XCD-aware bijective swizzle (nwg = 16384, % 8 == 0): XCD k gets a
    // contiguous band of logical blocks -> row-neighbor fmap reuse stays in
    // that XCD's private L2.
    const int nwg = BB * HH * 2;
    const int bid = blockIdx.x;
    const int blk = (bid & 7) * (nwg >> 3) + (bid >> 3);

    // block = half image row (256 pixels); 1 thread = 1 pixel
    const int row = blk >> 1;            // b*H + h
    const int h = row & (HH - 1);
    const int b = row >> 9;
    const int w0 = (blk & 1) << 8;       // 0 or 256

    // 71/512 is exactly representable; replaces the reference's divide.
    const float inv_s = 71.0f / 512.0f;
    const float c6 = 1.0f / 6.0f;

    __shared__ float2 S[NX];

    const int t = threadIdx.x;
    if (t < NX) {
        // row-constant Bv basis (Horner)
        float qy = (float)h * inv_s;
        float v = qy - floorf(qy);
        int py = (int)floorf(qy);
        float Bv0 = (((-v + 3.f) * v - 3.f) * v + 1.f) * c6;
        float Bv1 = ((3.f * v - 6.f) * v * v + 4.f) * c6;
        float Bv2 = (((-3.f * v + 3.f) * v + 3.f) * v + 1.f) * c6;
        float Bv3 = (v * v * v) * c6;

        const float* thx = theta + b * 2 * NY * NX; // theta[b,0]
        const float* thy = thx + NY * NX;           // theta[b,1]
        int base = py * NX + t;
        float sxv = Bv0 * thx[base] + Bv1 * thx[base + NX] +
                    Bv2 * thx[base + 2 * NX] + Bv3 * thx[base + 3 * NX];
        float syv = Bv0 * thy[base] + Bv1 * thy[base + NX] +
                    Bv2 * thy[base + 2 * NX] + Bv3 * thy[base + 3 * NX];
        S[t] = make_float2(sxv, syv);
    }
    __syncthreads();

    const int w = w0 + t;
    const float xw = (float)w;
    const float yh = (float)h;

    float qx = xw * inv_s;
    float u = qx - floorf(qx);
    int px = (int)floorf(qx);
    float Bu0 = (((-u + 3.f) * u - 3.f) * u + 1.f) * c6;
    float Bu1 = ((3.f * u - 6.f) * u * u + 4.f) * c6;
    float Bu2 = (((-3.f * u + 3.f) * u + 3.f) * u + 1.f) * c6;
    float Bu3 = (u * u * u) * c6;

    float2 s0 = S[px], s1 = S[px + 1], s2 = S[px + 2], s3 = S[px + 3];
    float dx = Bu0 * s0.x + Bu1 * s1.x + Bu2 * s2.x + Bu3 * s3.x;
    float dy = Bu0 * s0.y + Bu1 * s1.y + Bu2 * s2.y + Bu3 * s3.y;

    float xs = xw + dx;
    float ys = yh + dy;
    int x0 = (int)floorf(xs);
    int y0 = (int)floorf(ys);
    // reference clamp order: x1 from pre-clamp x0
    int x1 = min(max(x0 + 1, 0), WW - 1);
    int y1 = min(max(y0 + 1, 0), HH - 1);
    x0 = min(max(x0, 0), WW - 1);
    y0 = min(max(y0, 0), HH - 1);

    float wa = ((float)x1 - xs) * ((float)y1 - ys);
    float wb = ((float)x1 - xs) * (ys - (float)y0);
    float wc = (xs - (float)x0) * ((float)y1 - ys);
    float wd = (xs - (float)x0) * (ys - (float)y0);

    const float* fb = fmap + b * (HH * WW * CC);
    F3 Ia = *(const F3*)(fb + ((y0 << 9) + x0) * 3);
    F3 Ib = *(const F3*)(fb + ((y1 << 9) + x0) * 3);
    F3 Ic = *(const F3*)(fb + ((y0 << 9) + x1) * 3);
    F3 Id = *(const F3*)(fb + ((y1 << 9) + x1) * 3);

    const int pix = (row << 9) + w;
    float* op = out + pix * 3;
    __builtin_nontemporal_store(wa * Ia.a + wb * Ib.a + wc * Ic.a + wd * Id.a, op + 0);
    __builtin_nontemporal_store(wa * Ia.b + wb * Ib.b + wc * Ic.b + wd * Id.b, op + 1);
    __builtin_nontemporal_store(wa * Ia.c + wb * Ib.c + wc * Ic.c + wd * Id.c, op + 2);

    const int total = BB * HH * WW;
    __builtin_nontemporal_store(dx, delta_out + pix);
    __builtin_nontemporal_store(dy, delta_out + total + pix);
}

extern "C" void kernel_launch(void* const* d_in, const int* in_sizes, int n_in,
                              void* d_out, int out_size, void* d_ws, size_t ws_size,
                              hipStream_t stream) {
    const float* fmap  = (const float*)d_in[0];
    const float* theta = (const float*)d_in[1];
    float* out = (float*)d_out;
    float* delta = out + (size_t)BB * HH * WW * CC;

    dim3 grid(BB * HH * 2), block(256);
    stb_kernel<<<grid, block, 0, stream>>>(fmap, theta, out, delta);
}